// Round 5
// baseline (1493.419 us; speedup 1.0000x reference)
//
#include <hip/hip_runtime.h>
#include <hip/hip_bf16.h>

// GraphCAD forward on MI355X. All float I/O is f32.
// R11->R12: per-wave gather loops (R10 regs, R11 LDS pipeline) both ceiling
// at ~220-245us, latency-bound. k_edge already stages the SAME x[src] rows
// (2 rows/edge + a 64^3 GEMM) faster than k_nodeup gathers 1 row/edge. So the
// GIN aggregation moves INTO k_edge: after sampling, each wave walks its 16
// CSR slots (dst-sorted runs), accumulates ew*x[src] in f64, flushes one
// unsafeAtomicAdd f64 per lane per run into aggr[dst][lane]; x[src] re-reads
// are L2-hot. k_fix adds its ~50 deferred edges likewise. aggr ALIASES x64
// (dead from k_P<l> until k_bnapply<l> rewrites it) - zero extra workspace,
// one 32MB memset/layer. k_nodeup becomes k_gin: streaming aggr+self, f64
// matvec, BN partials - no gather. Aggregation operands identical to R10
// (f32 rows, f32 ew, f64 acc); only the f64 summation ORDER changes (~1e-15
// rel), 9 orders below the FIXTH=2e-3 decision guard.

#define D 64
#define BSZ 16
#define NPG 4096
#define NN (BSZ * NPG)   // 65536 nodes
#define NE (NN * 16)     // 1048576 edges
#define NL 2
#define NTILE (NE / 64)  // 16384

#define FIXTH 2e-3f
#define FLAGCAP 65536

// output layout (elements, f32)
#define OUT_X  0u
#define OUT_EW 4194304u
#define OUT_C  5242880u
#define OUT_XL 5243904u
#define OUT_CL 9438208u
#define OUT_PA 9439232u

__device__ __forceinline__ void atomAdd64(double* p, double v) { unsafeAtomicAdd(p, v); }

// ================= CSR build (dst is a static input; rebuilt per call) ======
__global__ __launch_bounds__(256) void k_deg(const int* __restrict__ edst,
                                             int* __restrict__ cnt) {
    int stride = gridDim.x * 256;
    for (int e = blockIdx.x * 256 + threadIdx.x; e < NE; e += stride)
        atomicAdd(&cnt[edst[e]], 1);
}

__global__ __launch_bounds__(256) void k_scan1(const int* __restrict__ cnt,
                                               int* __restrict__ rowptr,
                                               int* __restrict__ bsum) {
    __shared__ int sd[256];
    const int b = blockIdx.x, t = threadIdx.x;
    const int v = cnt[b * 256 + t];
    sd[t] = v;
    __syncthreads();
    for (int off = 1; off < 256; off <<= 1) {
        int tmp = (t >= off) ? sd[t - off] : 0;
        __syncthreads();
        sd[t] += tmp;
        __syncthreads();
    }
    rowptr[b * 256 + t] = sd[t] - v;  // exclusive
    if (t == 255) bsum[b] = sd[255];
}

__global__ __launch_bounds__(256) void k_scan2(int* __restrict__ bsum) {
    __shared__ int sd[256];
    const int t = threadIdx.x;
    const int v = bsum[t];
    sd[t] = v;
    __syncthreads();
    for (int off = 1; off < 256; off <<= 1) {
        int tmp = (t >= off) ? sd[t - off] : 0;
        __syncthreads();
        sd[t] += tmp;
        __syncthreads();
    }
    bsum[t] = sd[t] - v;  // exclusive
}

__global__ __launch_bounds__(256) void k_scan3(const int* __restrict__ bsum,
                                               int* __restrict__ rowptr,
                                               int* __restrict__ cursor) {
    const int i = blockIdx.x * 256 + threadIdx.x;
    const int r = rowptr[i] + bsum[blockIdx.x];
    rowptr[i] = r;
    cursor[i] = r;
    if (i == 0) rowptr[NN] = NE;
}

// fill CSR: slot -> original edge (eord), src (src_csr), dst (dst_csr).
__global__ __launch_bounds__(256) void k_fill(const int* __restrict__ esrc,
                                              const int* __restrict__ edst,
                                              int* __restrict__ cursor,
                                              int* __restrict__ eord,
                                              int* __restrict__ src_csr,
                                              int* __restrict__ dst_csr) {
    int stride = gridDim.x * 256;
    for (int e = blockIdx.x * 256 + threadIdx.x; e < NE; e += stride) {
        const int d = edst[e];
        int pos = atomicAdd(&cursor[d], 1);
        eord[pos] = e;
        src_csr[pos] = esrc[e];
        dst_csr[pos] = d;
    }
}

// ---- initial centroid: per-graph mean of x (f32 in, f64 out) ----
__global__ __launch_bounds__(256) void k_centroid0(const float* __restrict__ xin,
                                                   double* __restrict__ c64) {
    int g = blockIdx.x, tid = threadIdx.x;
    int r = tid >> 6, f = tid & 63;
    __shared__ double cr[4][D];
    double s = 0.0;
    for (int k = 0; k < NPG / 4; ++k) {
        size_t n = (size_t)g * NPG + (size_t)(4 * k + r);
        s += (double)xin[n * D + f];
    }
    cr[r][f] = s;
    __syncthreads();
    if (tid < D)
        c64[g * D + tid] = (cr[0][tid] + cr[1][tid] + cr[2][tid] + cr[3][tid]) * (1.0 / NPG);
}

// ---- qb = c @ W1b, qc = c @ W1c (per graph, f64) ----
__global__ __launch_bounds__(256) void k_qbc(const double* __restrict__ c64,
                                             const float* __restrict__ epW1,
                                             double* __restrict__ qb, double* __restrict__ qc) {
    int gj = blockIdx.x * 256 + threadIdx.x;
    if (gj >= BSZ * D) return;
    int g = gj >> 6, j = gj & 63;
    double sb = 0.0, sc = 0.0;
#pragma unroll
    for (int i = 0; i < D; ++i) {
        double cv = c64[g * D + i];
        sb += cv * (double)epW1[(D + i) * D + j];
        sc += cv * (double)epW1[(2 * D + i) * D + j];
    }
    qb[gj] = sb;
    qc[gj] = sc;
}

// ---- P'_b = x@W1b - qb[g], P'_c = x@W1c - qc[g]; f64 compute, f32 store ----
template <int LAYER>
__global__ __launch_bounds__(256) void k_P(const float* __restrict__ xin,
                                           const double* __restrict__ x64,
                                           const float* __restrict__ epW1,
                                           const double* __restrict__ qb,
                                           const double* __restrict__ qc,
                                           float* __restrict__ Pb, float* __restrict__ Pc,
                                           double* __restrict__ bnacc) {
    if (blockIdx.x == 0 && threadIdx.x < 128) bnacc[threadIdx.x] = 0.0;
    __shared__ double wb[D * D];
    __shared__ double wc[D * D];
    __shared__ double xrow[4][D];
    int tid = threadIdx.x, w = tid >> 6, j = tid & 63;
    for (int idx = tid; idx < D * D; idx += 256) {
        int i = idx >> 6, c = idx & 63;
        wb[idx] = (double)epW1[(D + i) * D + c];
        wc[idx] = (double)epW1[(2 * D + i) * D + c];
    }
    __syncthreads();
    for (int grp = blockIdx.x; grp < NN / 4; grp += gridDim.x) {
        size_t n = (size_t)grp * 4 + w;
        xrow[w][j] = (LAYER == 0) ? (double)xin[n * D + j] : x64[n * D + j];
        __syncthreads();
        double pb = 0.0, pc = 0.0;
#pragma unroll
        for (int i = 0; i < D; ++i) {
            double xv = xrow[w][i];
            pb += xv * wb[i * D + j];
            pc += xv * wc[i * D + j];
        }
        const int g = (int)(n >> 12);
        Pb[n * D + j] = (float)(pb - qb[g * D + j]);
        Pc[n * D + j] = (float)(pc - qc[g * D + j]);
        __syncthreads();
    }
}

// ---- edge scorer + fused GIN aggregation, CSR order ----
// f32 tile GEMM + sample; near-threshold edges (|score+g| < FIXTH) deferred
// to k_fix. After sampling: per-wave run-accumulate ew*x[src] (f64) over its
// 16 dst-sorted slots, flush one atomicAdd f64/lane per run into aggr.
// LDS: A f32 [64][68] 17KB (reused as f32 sred), W f32 [64][68] 17KB, ewb.
template <int LAYER>
__global__ __launch_bounds__(256, 4) void k_edge(const float* __restrict__ xsrc,
                                                 const int* __restrict__ src_csr,
                                                 const int* __restrict__ dst_csr,
                                                 const int* __restrict__ eord,
                                                 const float* __restrict__ ewin,
                                                 float* __restrict__ ew_csr,
                                                 const float* __restrict__ unoise,
                                                 const float* __restrict__ epW1,
                                                 const float* __restrict__ epb1,
                                                 const float* __restrict__ epW2,
                                                 const float* __restrict__ epb2,
                                                 const float* __restrict__ alphap,
                                                 const float* __restrict__ Pb32,
                                                 const float* __restrict__ Pc32,
                                                 int* __restrict__ flagcnt,
                                                 int* __restrict__ flaglist,
                                                 double* __restrict__ aggr,
                                                 float* __restrict__ out) {
    const int t = threadIdx.x;
    const int tx = t & 15, ty = t >> 4;
    const int w = t >> 6, lane = t & 63;

    __shared__ __align__(16) float ldsA[64 * 68];  // |dx| [dim][slot]
    __shared__ float ldsW[64 * 68];                // W1a [k][j]
    __shared__ float ewb[64];                      // sampled ew per slot

    for (int idx = t; idx < D * D; idx += 256) {
        int k = idx >> 6, j = idx & 63;
        ldsW[k * 68 + j] = epW1[idx];
    }
    float b1f[4], w2f[4];
#pragma unroll
    for (int c = 0; c < 4; ++c) {
        b1f[c] = epb1[4 * tx + c];
        w2f[c] = epW2[4 * tx + c];
    }
    const float b2v = epb2[0];
    const float alpha = alphap[0];
    __syncthreads();

    const int eloc = t >> 2, q = t & 3;

    for (int tile = blockIdx.x; tile < NTILE; tile += gridDim.x) {
        const int base = tile * 64;

        // ---- stage |x_d - x_s| (f32, transposed). d-rows run-repeat (L1). --
        {
            const int pos = base + eloc;
            const int s = src_csr[pos], d = dst_csr[pos];
            const float* rs = xsrc + (size_t)s * D + q * 16;
            const float* rd = xsrc + (size_t)d * D + q * 16;
#pragma unroll
            for (int c = 0; c < 4; ++c) {
                const float4 fd = *(const float4*)(rd + 4 * c);
                const float4 fs = *(const float4*)(rs + 4 * c);
                const int dim = q * 16 + 4 * c;
                ldsA[(dim + 0) * 68 + eloc] = fabsf(fd.x - fs.x);
                ldsA[(dim + 1) * 68 + eloc] = fabsf(fd.y - fs.y);
                ldsA[(dim + 2) * 68 + eloc] = fabsf(fd.z - fs.z);
                ldsA[(dim + 3) * 68 + eloc] = fabsf(fd.w - fs.w);
            }
        }
        __syncthreads();

        // ---- 64x64x64 GEMM: f32 inputs, f32 accumulate, 4x4 per thread ----
        float acc[4][4];
#pragma unroll
        for (int r = 0; r < 4; ++r)
#pragma unroll
            for (int c = 0; c < 4; ++c) acc[r][c] = 0.0f;

#pragma unroll 4
        for (int k = 0; k < 64; ++k) {
            const float4 af = *(const float4*)&ldsA[k * 68 + 4 * ty];
            const float4 wf = *(const float4*)&ldsW[k * 68 + 4 * tx];
            const float av[4] = {af.x, af.y, af.z, af.w};
            const float wv[4] = {wf.x, wf.y, wf.z, wf.w};
#pragma unroll
            for (int r = 0; r < 4; ++r)
#pragma unroll
                for (int c = 0; c < 4; ++c) acc[r][c] += av[r] * wv[c];
        }
        __syncthreads();  // A dead -> reuse as f32 sred

        float* sred = ldsA;
        // ---- epilogue: + P' terms, +b1, relu, * w2, partial sums ----
#pragma unroll
        for (int r = 0; r < 4; ++r) {
            const int pos = base + 4 * ty + r;
            const int s = src_csr[pos], d = dst_csr[pos];
            const float4 pb = *(const float4*)(Pb32 + (size_t)d * D + 4 * tx);
            const float4 pc = *(const float4*)(Pc32 + (size_t)s * D + 4 * tx);
            float part = 0.0f;
            float h;
            h = acc[r][0] + pb.x + pc.x + b1f[0];
            if (h > 0.0f) part += h * w2f[0];
            h = acc[r][1] + pb.y + pc.y + b1f[1];
            if (h > 0.0f) part += h * w2f[1];
            h = acc[r][2] + pb.z + pc.z + b1f[2];
            if (h > 0.0f) part += h * w2f[2];
            h = acc[r][3] + pb.w + pc.w + b1f[3];
            if (h > 0.0f) part += h * w2f[3];
            sred[(4 * ty + r) * 17 + tx] = part;
        }
        __syncthreads();

        // ---- score reduce + RelaxedBernoulli sample (one lane per slot) ----
        if (t < 64) {
            float sc_ = b2v;
#pragma unroll
            for (int i = 0; i < 16; ++i) sc_ += sred[t * 17 + i];
            const int pos = base + t;
            const int e = eord[pos];
            const float u = unoise[(size_t)LAYER * NE + e];
            const float gn = logf(u) - log1pf(-u);
            const float mar = sc_ + gn;  // decision margin; samp == (mar > 0)
            bool deferred = false;
            if (fabsf(mar) < FIXTH) {
                int slot = atomicAdd(flagcnt, 1);
                if (slot < FLAGCAP) {
                    flaglist[slot] = pos;
                    deferred = true;  // k_fix decides + writes + aggregates
                }
            }
            float ewrec = 0.0f;
            if (!deferred) {
                const float pre = 1.0f / (1.0f + expf(-sc_));
                const bool samp = mar > 0.0f;
                const float ewo = (LAYER == 0) ? ewin[e] : ew_csr[pos];
                const float ewn = samp ? alpha * ewo + (1.0f - alpha) * pre : 0.0f;
                ew_csr[pos] = ewn;
                ewrec = ewn;
                if (LAYER == NL - 1) {
                    out[OUT_EW + (size_t)e] = ewn;
                    out[OUT_PA + (size_t)e] = pre;
                }
            }
            ewb[t] = ewrec;
        }
        __syncthreads();

        // ---- fused GIN aggregation: wave w owns slots [16w,16w+16) ----
        // dst_csr sorted -> contiguous runs; f64 run-accumulate, atomic flush.
        {
            const int s0 = 16 * w;
            double accd = 0.0;
            int curd = dst_csr[base + s0];
#pragma unroll
            for (int s = s0; s < s0 + 16; ++s) {
                const int pos = base + s;
                const int dcur = dst_csr[pos];
                if (dcur != curd) {  // wave-uniform branch
                    atomAdd64(&aggr[(size_t)curd * D + lane], accd);
                    accd = 0.0;
                    curd = dcur;
                }
                accd += (double)ewb[s] * (double)xsrc[(size_t)src_csr[pos] * D + lane];
            }
            atomAdd64(&aggr[(size_t)curd * D + lane], accd);
        }
        __syncthreads();
    }
}

// ---- exact f64 re-decision for near-threshold edges (one wave per edge) ----
// Also contributes the edge's ewn * x[src] into aggr (skipped in k_edge).
template <int LAYER>
__global__ __launch_bounds__(256) void k_fix(const float* __restrict__ xsrc,
                                             const int* __restrict__ src_csr,
                                             const int* __restrict__ dst_csr,
                                             const int* __restrict__ eord,
                                             const float* __restrict__ ewin,
                                             float* __restrict__ ew_csr,
                                             const float* __restrict__ unoise,
                                             const float* __restrict__ epW1,
                                             const float* __restrict__ epb1,
                                             const float* __restrict__ epW2,
                                             const float* __restrict__ epb2,
                                             const float* __restrict__ alphap,
                                             const float* __restrict__ Pb32,
                                             const float* __restrict__ Pc32,
                                             const int* __restrict__ flagcnt,
                                             const int* __restrict__ flaglist,
                                             double* __restrict__ aggr,
                                             float* __restrict__ out) {
    const int n = min(flagcnt[0], FLAGCAP);
    __shared__ float dxs[4][D];
    const int w = threadIdx.x >> 6, lane = threadIdx.x & 63;
    const int nw = gridDim.x * 4;
    for (int i = blockIdx.x * 4 + w; i < n; i += nw) {
        const int pos = flaglist[i];
        const int s = src_csr[pos], d = dst_csr[pos];
        const float xsv = xsrc[(size_t)s * D + lane];
        // |dx| from the same f32 inputs the main kernel staged
        dxs[w][lane] = fabsf(xsrc[(size_t)d * D + lane] - xsv);
        // wave-internal broadcast (same-wave DS in-order)
        double h = 0.0;
#pragma unroll
        for (int k = 0; k < D; ++k) h += (double)dxs[w][k] * (double)epW1[k * D + lane];
        h += (double)Pb32[(size_t)d * D + lane] + (double)Pc32[(size_t)s * D + lane] +
             (double)epb1[lane];
        double part = (h > 0.0) ? h * (double)epW2[lane] : 0.0;
#pragma unroll
        for (int off = 32; off; off >>= 1) part += __shfl_xor(part, off);
        // all lanes now hold the full reduction -> compute scalars uniformly
        const double sc_ = part + (double)epb2[0];
        const int e = eord[pos];
        const double u = (double)unoise[(size_t)LAYER * NE + e];
        const double gn = log(u) - log1p(-u);
        const double pre = 1.0 / (1.0 + exp(-sc_));
        const bool samp = (sc_ + gn) > 0.0;
        const double ewo = (LAYER == 0) ? (double)ewin[e] : (double)ew_csr[pos];
        const double alpha = (double)alphap[0];
        const double ewn = samp ? alpha * ewo + (1.0 - alpha) * pre : 0.0;
        if (lane == 0) {
            ew_csr[pos] = (float)ewn;
            if (LAYER == NL - 1) {
                out[OUT_EW + (size_t)e] = (float)ewn;
                out[OUT_PA + (size_t)e] = (float)pre;
            }
        }
        if (ewn != 0.0) atomAdd64(&aggr[(size_t)d * D + lane], ewn * (double)xsv);
    }
}

// ---- GIN node update: streaming (no gather): (self + aggr) @ W, relu, BN --
template <int LAYER>
__global__ __launch_bounds__(256) void k_gin(const float* __restrict__ xsrc,
                                             const double* __restrict__ aggr,
                                             const float* __restrict__ ginW,
                                             const float* __restrict__ ginB,
                                             double* __restrict__ xh,
                                             double* __restrict__ bnacc) {
    __shared__ float wg[D * D];
    __shared__ double rowbuf[4][D];
    const int t = threadIdx.x, w = t >> 6, lane = t & 63;
    for (int idx = t; idx < D * D; idx += 256) wg[idx] = ginW[LAYER * D * D + idx];
    const double bj = (double)ginB[LAYER * D + lane];
    __syncthreads();
    double s1 = 0.0, s2 = 0.0;
    const int nwaves = gridDim.x * 4;
    for (int n = blockIdx.x * 4 + w; n < NN; n += nwaves) {
        const double acc = (double)xsrc[(size_t)n * D + lane] + aggr[(size_t)n * D + lane];
        rowbuf[w][lane] = acc;  // wave-internal broadcast (same-wave DS in-order)
        double h = bj;
#pragma unroll
        for (int i = 0; i < D; ++i) h += rowbuf[w][i] * (double)wg[i * D + lane];
        h = h > 0.0 ? h : 0.0;
        xh[(size_t)n * D + lane] = h;
        s1 += h;
        s2 += h * h;
    }
    atomAdd64(&bnacc[lane], s1);
    atomAdd64(&bnacc[64 + lane], s2);
}

// ---- BN finalize ----
__global__ __launch_bounds__(64) void k_bnfin(int layer, const float* __restrict__ gamma,
                                              const float* __restrict__ beta,
                                              const double* __restrict__ bnacc,
                                              double* __restrict__ bnsc) {
    int j = threadIdx.x;
    double mu = bnacc[j] * (1.0 / NN);
    double var = bnacc[64 + j] * (1.0 / NN) - mu * mu;
    double sc = (double)gamma[layer * D + j] / sqrt(var + 1e-5);
    bnsc[j] = sc;
    bnsc[64 + j] = (double)beta[layer * D + j] - mu * sc;
}

// ---- BN apply -> x64 (+x32 mirror for edge staging; final out) ----
template <int LAYER>
__global__ __launch_bounds__(256) void k_bnapply(const double* __restrict__ bnsc,
                                                 const double* __restrict__ xh,
                                                 double* __restrict__ x64,
                                                 float* __restrict__ x32,
                                                 float* __restrict__ out) {
    size_t stride = (size_t)gridDim.x * 256;
    for (size_t i = (size_t)blockIdx.x * 256 + threadIdx.x; i < (size_t)NN * D; i += stride) {
        int j = (int)(i & 63);
        double v = bnsc[j] * xh[i] + bnsc[64 + j];
        x64[i] = v;
        if (LAYER == 0) x32[i] = (float)v;
        if (LAYER == NL - 1) out[OUT_X + i] = (float)v;
    }
}

// ---- attention pooling, parallelized: 4 kernels ----
__global__ __launch_bounds__(256) void k_att1(const double* __restrict__ x64,
                                              const double* __restrict__ c64,
                                              double* __restrict__ sc,
                                              double* __restrict__ bmax) {
    const int blk = blockIdx.x, t = threadIdx.x, w = t >> 6, lane = t & 63;
    const int g = blk >> 6;
    __shared__ double wmax[4];
    const double cj = c64[g * D + lane];
    double locmax = -1e300;
    for (int m = 0; m < 16; ++m) {
        const int n = blk * 64 + w * 16 + m;
        double v = x64[(size_t)n * D + lane] * cj;
#pragma unroll
        for (int off = 32; off; off >>= 1) v += __shfl_xor(v, off);
        if (lane == 0) sc[n] = v;
        locmax = fmax(locmax, v);
    }
    if (lane == 0) wmax[w] = locmax;
    __syncthreads();
    if (t == 0) bmax[blk] = fmax(fmax(wmax[0], wmax[1]), fmax(wmax[2], wmax[3]));
}

__global__ __launch_bounds__(64) void k_att2(const double* __restrict__ bmax,
                                             double* __restrict__ mxg,
                                             double* __restrict__ num,
                                             double* __restrict__ den) {
    const int g = blockIdx.x, t = threadIdx.x;
    double m = bmax[g * 64 + t];
#pragma unroll
    for (int off = 32; off; off >>= 1) m = fmax(m, __shfl_xor(m, off));
    if (t == 0) {
        mxg[g] = m;
        den[g] = 0.0;
    }
    num[g * D + t] = 0.0;
}

__global__ __launch_bounds__(256) void k_att3(const double* __restrict__ x64,
                                              const double* __restrict__ sc,
                                              const double* __restrict__ mxg,
                                              double* __restrict__ num,
                                              double* __restrict__ den) {
    const int blk = blockIdx.x, t = threadIdx.x, w = t >> 6, lane = t & 63;
    const int g = blk >> 6;
    __shared__ double cp[4][D];
    __shared__ double wes[4];
    const double mx = mxg[g];
    double accj = 0.0, esum = 0.0;
    for (int m = 0; m < 16; ++m) {
        const int n = blk * 64 + w * 16 + m;
        const double e = exp(sc[n] - mx);
        accj += e * x64[(size_t)n * D + lane];
        esum += e;
    }
    cp[w][lane] = accj;
    if (lane == 0) wes[w] = esum;
    __syncthreads();
    if (t < D) {
        atomAdd64(&num[g * D + t], cp[0][t] + cp[1][t] + cp[2][t] + cp[3][t]);
        if (t == 0) atomAdd64(&den[g], wes[0] + wes[1] + wes[2] + wes[3]);
    }
}

__global__ __launch_bounds__(64) void k_att4(const double* __restrict__ num,
                                             const double* __restrict__ den,
                                             double* __restrict__ c64) {
    const int g = blockIdx.x, t = threadIdx.x;
    c64[g * D + t] = num[g * D + t] / den[g];
}

// ---- head: relu(x@W1+b1)@W2+b2 for all nodes + 16 centroid rows (f32) ----
__global__ __launch_bounds__(256) void k_head(const double* __restrict__ x64,
                                              const double* __restrict__ c64,
                                              const float* __restrict__ hW1,
                                              const float* __restrict__ hb1,
                                              const float* __restrict__ hW2,
                                              const float* __restrict__ hb2,
                                              float* __restrict__ out) {
    __shared__ float w1[D * D];
    __shared__ float w2[D * D];
    __shared__ float xr[4][D];
    __shared__ float hr[4][D];
    int tid = threadIdx.x, w = tid >> 6, j = tid & 63;
    for (int idx = tid; idx < D * D; idx += 256) {
        w1[idx] = hW1[idx];
        w2[idx] = hW2[idx];
    }
    const float b1j = hb1[j];
    const float b2j = hb2[j];
    __syncthreads();
    const int ROWS = NN + BSZ;
    for (int grp = blockIdx.x; grp * 4 < ROWS; grp += gridDim.x) {
        int r = grp * 4 + w;
        bool valid = r < ROWS;
        float xv = 0.f;
        if (valid)
            xv = (r < NN) ? (float)x64[(size_t)r * D + j] : (float)c64[(size_t)(r - NN) * D + j];
        xr[w][j] = xv;
        __syncthreads();
        if (valid) {
            float h = b1j;
#pragma unroll
            for (int i = 0; i < D; ++i) h += xr[w][i] * w1[i * D + j];
            hr[w][j] = h > 0.f ? h : 0.f;
        }
        __syncthreads();
        if (valid) {
            float o = b2j;
#pragma unroll
            for (int i = 0; i < D; ++i) o += hr[w][i] * w2[i * D + j];
            if (r < NN) {
                out[OUT_XL + (size_t)r * D + j] = o;
            } else {
                size_t cr = (size_t)(r - NN) * D + j;
                out[OUT_CL + cr] = o;
                out[OUT_C + cr] = (float)c64[cr];
            }
        }
        __syncthreads();
    }
}

extern "C" void kernel_launch(void* const* d_in, const int* in_sizes, int n_in,
                              void* d_out, int out_size, void* d_ws, size_t ws_size,
                              hipStream_t stream) {
    const float* xin    = (const float*)d_in[0];
    const int*   ei     = (const int*)d_in[1];
    const float* ewin   = (const float*)d_in[2];
    const float* unoise = (const float*)d_in[5];
    const float* epW1   = (const float*)d_in[6];
    const float* epb1   = (const float*)d_in[7];
    const float* epW2   = (const float*)d_in[8];
    const float* epb2   = (const float*)d_in[9];
    const float* alphap = (const float*)d_in[10];
    const float* ginW   = (const float*)d_in[11];
    const float* ginB   = (const float*)d_in[12];
    const float* bng    = (const float*)d_in[13];
    const float* bnb    = (const float*)d_in[14];
    const float* hW1    = (const float*)d_in[15];
    const float* hb1    = (const float*)d_in[16];
    const float* hW2    = (const float*)d_in[17];
    const float* hb2    = (const float*)d_in[18];
    float* out = (float*)d_out;
    const int* esrc = ei;
    const int* edst = ei + NE;

    char* ws = (char*)d_ws;
    const size_t SZ = (size_t)NN * D * sizeof(double);  // 33554432
    double* x64  = (double*)(ws);
    double* aggr = x64;  // ALIAS: x64 dead from after k_P<l> until k_bnapply<l>
    // Pb/Pc (k_P->k_fix) and xh (k_gin->k_bnapply): disjoint live ranges.
    float*  Pb32 = (float*)(ws + SZ);
    float*  Pc32 = (float*)(ws + SZ + SZ / 2);
    double* xh   = (double*)(ws + SZ);
    float*  x32  = (float*)(ws + 2 * SZ);                       // NN*D*4 = 16MB
    float*  ew_csr = (float*)(ws + 2 * SZ + SZ / 2);            // NE*4 (slot is NE*8)
    double* sc   = (double*)(ws + 2 * SZ + SZ / 2 + (size_t)NE * 8);  // NN*8
    char*   p    = ws + 2 * SZ + SZ / 2 + (size_t)NE * 8 + (size_t)NN * 8;
    double* c64  = (double*)p;          p += BSZ * D * 8;
    double* qb   = (double*)p;          p += BSZ * D * 8;
    double* qc   = (double*)p;          p += BSZ * D * 8;
    double* bnacc = (double*)p;         p += 128 * 8;
    double* bnsc  = (double*)p;         p += 128 * 8;
    double* bmax  = (double*)p;         p += 1024 * 8;
    double* mxg   = (double*)p;         p += 16 * 8;
    double* num   = (double*)p;         p += BSZ * D * 8;
    double* den   = (double*)p;         p += 16 * 8;
    // CSR
    int* cnt     = (int*)p;             p += (size_t)NN * 4;
    int* rowptr  = (int*)p;             p += (size_t)(NN + 1) * 4 + 4;
    int* cursor  = (int*)p;             p += (size_t)NN * 4;
    int* bsum    = (int*)p;             p += 256 * 4;
    int* eord    = (int*)p;             p += (size_t)NE * 4;
    int* src_csr = (int*)p;             p += (size_t)NE * 4;
    int* dst_csr = (int*)p;             p += (size_t)NE * 4;
    // near-threshold fixup list
    int* flagcnt  = (int*)p;            p += 8;
    int* flaglist = (int*)p;            p += (size_t)FLAGCAP * 4;

    // ---- CSR build (dst static) ----
    hipMemsetAsync(cnt, 0, (size_t)NN * 4, stream);
    k_deg<<<1024, 256, 0, stream>>>(edst, cnt);
    k_scan1<<<256, 256, 0, stream>>>(cnt, rowptr, bsum);
    k_scan2<<<1, 256, 0, stream>>>(bsum);
    k_scan3<<<256, 256, 0, stream>>>(bsum, rowptr, cursor);
    k_fill<<<1024, 256, 0, stream>>>(esrc, edst, cursor, eord, src_csr, dst_csr);

    k_centroid0<<<BSZ, 256, 0, stream>>>(xin, c64);

    // ---------------- layer 0 ----------------
    k_qbc<<<4, 256, 0, stream>>>(c64, epW1, qb, qc);
    k_P<0><<<1024, 256, 0, stream>>>(xin, x64, epW1, qb, qc, Pb32, Pc32, bnacc);
    hipMemsetAsync(flagcnt, 0, 4, stream);
    hipMemsetAsync(aggr, 0, SZ, stream);  // x64 dead until k_bnapply<0>
    k_edge<0><<<2048, 256, 0, stream>>>(xin, src_csr, dst_csr, eord, ewin, ew_csr, unoise,
                                        epW1, epb1, epW2, epb2, alphap, Pb32, Pc32,
                                        flagcnt, flaglist, aggr, out);
    k_fix<0><<<64, 256, 0, stream>>>(xin, src_csr, dst_csr, eord, ewin, ew_csr, unoise,
                                     epW1, epb1, epW2, epb2, alphap, Pb32, Pc32,
                                     flagcnt, flaglist, aggr, out);
    k_gin<0><<<2048, 256, 0, stream>>>(xin, aggr, ginW, ginB, xh, bnacc);
    k_bnfin<<<1, 64, 0, stream>>>(0, bng, bnb, bnacc, bnsc);
    k_bnapply<0><<<2048, 256, 0, stream>>>(bnsc, xh, x64, x32, out);
    k_att1<<<1024, 256, 0, stream>>>(x64, c64, sc, bmax);
    k_att2<<<16, 64, 0, stream>>>(bmax, mxg, num, den);
    k_att3<<<1024, 256, 0, stream>>>(x64, sc, mxg, num, den);
    k_att4<<<16, 64, 0, stream>>>(num, den, c64);

    // ---------------- layer 1 ----------------
    k_qbc<<<4, 256, 0, stream>>>(c64, epW1, qb, qc);
    k_P<1><<<1024, 256, 0, stream>>>(xin, x64, epW1, qb, qc, Pb32, Pc32, bnacc);
    hipMemsetAsync(flagcnt, 0, 4, stream);
    hipMemsetAsync(aggr, 0, SZ, stream);  // after k_P<1>'s x64 reads
    k_edge<1><<<2048, 256, 0, stream>>>(x32, src_csr, dst_csr, eord, ewin, ew_csr, unoise,
                                        epW1, epb1, epW2, epb2, alphap, Pb32, Pc32,
                                        flagcnt, flaglist, aggr, out);
    k_fix<1><<<64, 256, 0, stream>>>(x32, src_csr, dst_csr, eord, ewin, ew_csr, unoise,
                                     epW1, epb1, epW2, epb2, alphap, Pb32, Pc32,
                                     flagcnt, flaglist, aggr, out);
    k_gin<1><<<2048, 256, 0, stream>>>(x32, aggr, ginW, ginB, xh, bnacc);
    k_bnfin<<<1, 64, 0, stream>>>(1, bng, bnb, bnacc, bnsc);
    k_bnapply<1><<<2048, 256, 0, stream>>>(bnsc, xh, x64, x32, out);
    k_att1<<<1024, 256, 0, stream>>>(x64, c64, sc, bmax);
    k_att2<<<16, 64, 0, stream>>>(bmax, mxg, num, den);
    k_att3<<<1024, 256, 0, stream>>>(x64, sc, mxg, num, den);
    k_att4<<<16, 64, 0, stream>>>(num, den, c64);

    // ---------------- heads + centroid output ----------------
    k_head<<<2048, 256, 0, stream>>>(x64, c64, hW1, hb1, hW2, hb2, out);
}

// Round 6
// 1066.810 us; speedup vs baseline: 1.3999x; 1.3999x over previous
//
#include <hip/hip_runtime.h>
#include <hip/hip_bf16.h>

// GraphCAD forward on MI355X. All float I/O is f32.
// R12->R13: R12's fused aggregation regressed (k_edge +120us each: atomics +
// extra sync + L2 thrash). Revert to R10 structure (best, 1261us) and fix
// k_nodeup's memory-parallelism SHAPE instead: k_edge's staging is fast
// because one load instruction touches 16 rows (lane->(edge,quarter));
// k_nodeup touched 1 row/instr (lane=dim) with FMA-drains between groups.
// New k_nodeup: lane=(slot e=0..3, quarter q=0..15); first 16 edges = 4
// float4-load instrs x 4 rows each, all issued before any use (named
// float4s, no arrays -> nothing to spill); f64 acc per (slot,4dims);
// tree-reduce slots via 2 shfl_xor; add self; 16-lane rowbuf write; f64
// matvec unchanged. Tail deg>16 in masked chunks of 4. All changes to f64
// summation ORDER only (~1e-16 rel) on continuous paths. Also: parallel
// k_centroid0 (128 blocks + f64 atomics, pre-zeroed c64) and block-level
// LDS pre-reduction of bnacc atomics.

#define D 64
#define BSZ 16
#define NPG 4096
#define NN (BSZ * NPG)   // 65536 nodes
#define NE (NN * 16)     // 1048576 edges
#define NL 2
#define NTILE (NE / 64)  // 16384

#define FIXTH 2e-3f
#define FLAGCAP 65536

// output layout (elements, f32)
#define OUT_X  0u
#define OUT_EW 4194304u
#define OUT_C  5242880u
#define OUT_XL 5243904u
#define OUT_CL 9438208u
#define OUT_PA 9439232u

__device__ __forceinline__ void atomAdd64(double* p, double v) { unsafeAtomicAdd(p, v); }

// ================= CSR build (dst is a static input; rebuilt per call) ======
__global__ __launch_bounds__(256) void k_deg(const int* __restrict__ edst,
                                             int* __restrict__ cnt) {
    int stride = gridDim.x * 256;
    for (int e = blockIdx.x * 256 + threadIdx.x; e < NE; e += stride)
        atomicAdd(&cnt[edst[e]], 1);
}

__global__ __launch_bounds__(256) void k_scan1(const int* __restrict__ cnt,
                                               int* __restrict__ rowptr,
                                               int* __restrict__ bsum) {
    __shared__ int sd[256];
    const int b = blockIdx.x, t = threadIdx.x;
    const int v = cnt[b * 256 + t];
    sd[t] = v;
    __syncthreads();
    for (int off = 1; off < 256; off <<= 1) {
        int tmp = (t >= off) ? sd[t - off] : 0;
        __syncthreads();
        sd[t] += tmp;
        __syncthreads();
    }
    rowptr[b * 256 + t] = sd[t] - v;  // exclusive
    if (t == 255) bsum[b] = sd[255];
}

__global__ __launch_bounds__(256) void k_scan2(int* __restrict__ bsum) {
    __shared__ int sd[256];
    const int t = threadIdx.x;
    const int v = bsum[t];
    sd[t] = v;
    __syncthreads();
    for (int off = 1; off < 256; off <<= 1) {
        int tmp = (t >= off) ? sd[t - off] : 0;
        __syncthreads();
        sd[t] += tmp;
        __syncthreads();
    }
    bsum[t] = sd[t] - v;  // exclusive
}

__global__ __launch_bounds__(256) void k_scan3(const int* __restrict__ bsum,
                                               int* __restrict__ rowptr,
                                               int* __restrict__ cursor) {
    const int i = blockIdx.x * 256 + threadIdx.x;
    const int r = rowptr[i] + bsum[blockIdx.x];
    rowptr[i] = r;
    cursor[i] = r;
    if (i == 0) rowptr[NN] = NE;
}

// fill CSR: slot -> original edge (eord), src (src_csr), dst (dst_csr).
__global__ __launch_bounds__(256) void k_fill(const int* __restrict__ esrc,
                                              const int* __restrict__ edst,
                                              int* __restrict__ cursor,
                                              int* __restrict__ eord,
                                              int* __restrict__ src_csr,
                                              int* __restrict__ dst_csr) {
    int stride = gridDim.x * 256;
    for (int e = blockIdx.x * 256 + threadIdx.x; e < NE; e += stride) {
        const int d = edst[e];
        int pos = atomicAdd(&cursor[d], 1);
        eord[pos] = e;
        src_csr[pos] = esrc[e];
        dst_csr[pos] = d;
    }
}

// ---- initial centroid: per-graph mean of x (f32 in, f64 out), 8 blocks/graph
__global__ __launch_bounds__(256) void k_centroid0(const float* __restrict__ xin,
                                                   double* __restrict__ c64) {
    const int g = blockIdx.x >> 3, sub = blockIdx.x & 7, tid = threadIdx.x;
    const int r = tid >> 6, f = tid & 63;
    __shared__ double cr[4][D];
    double s = 0.0;
    for (int k = 0; k < NPG / 8 / 4; ++k) {
        size_t n = (size_t)g * NPG + (size_t)(sub * (NPG / 8) + 4 * k + r);
        s += (double)xin[n * D + f];
    }
    cr[r][f] = s;
    __syncthreads();
    if (tid < D)
        atomAdd64(&c64[g * D + tid],
                  (cr[0][tid] + cr[1][tid] + cr[2][tid] + cr[3][tid]) * (1.0 / NPG));
}

// ---- qb = c @ W1b, qc = c @ W1c (per graph, f64) ----
__global__ __launch_bounds__(256) void k_qbc(const double* __restrict__ c64,
                                             const float* __restrict__ epW1,
                                             double* __restrict__ qb, double* __restrict__ qc) {
    int gj = blockIdx.x * 256 + threadIdx.x;
    if (gj >= BSZ * D) return;
    int g = gj >> 6, j = gj & 63;
    double sb = 0.0, sc = 0.0;
#pragma unroll
    for (int i = 0; i < D; ++i) {
        double cv = c64[g * D + i];
        sb += cv * (double)epW1[(D + i) * D + j];
        sc += cv * (double)epW1[(2 * D + i) * D + j];
    }
    qb[gj] = sb;
    qc[gj] = sc;
}

// ---- P'_b = x@W1b - qb[g], P'_c = x@W1c - qc[g]; f64 compute, f32 store ----
template <int LAYER>
__global__ __launch_bounds__(256) void k_P(const float* __restrict__ xin,
                                           const double* __restrict__ x64,
                                           const float* __restrict__ epW1,
                                           const double* __restrict__ qb,
                                           const double* __restrict__ qc,
                                           float* __restrict__ Pb, float* __restrict__ Pc,
                                           double* __restrict__ bnacc) {
    if (blockIdx.x == 0 && threadIdx.x < 128) bnacc[threadIdx.x] = 0.0;
    __shared__ double wb[D * D];
    __shared__ double wc[D * D];
    __shared__ double xrow[4][D];
    int tid = threadIdx.x, w = tid >> 6, j = tid & 63;
    for (int idx = tid; idx < D * D; idx += 256) {
        int i = idx >> 6, c = idx & 63;
        wb[idx] = (double)epW1[(D + i) * D + c];
        wc[idx] = (double)epW1[(2 * D + i) * D + c];
    }
    __syncthreads();
    for (int grp = blockIdx.x; grp < NN / 4; grp += gridDim.x) {
        size_t n = (size_t)grp * 4 + w;
        xrow[w][j] = (LAYER == 0) ? (double)xin[n * D + j] : x64[n * D + j];
        __syncthreads();
        double pb = 0.0, pc = 0.0;
#pragma unroll
        for (int i = 0; i < D; ++i) {
            double xv = xrow[w][i];
            pb += xv * wb[i * D + j];
            pc += xv * wc[i * D + j];
        }
        const int g = (int)(n >> 12);
        Pb[n * D + j] = (float)(pb - qb[g * D + j]);
        Pc[n * D + j] = (float)(pc - qc[g * D + j]);
        __syncthreads();
    }
}

// ---- edge scorer, CSR order: all-f32 tile GEMM + sample; near-threshold
// ---- edges (|score+g| < FIXTH) deferred to k_fix for exact f64 decision.
// LDS: A f32 [64][68] 17KB (reused as f32 sred), W f32 [64][68] 17KB.
template <int LAYER>
__global__ __launch_bounds__(256, 4) void k_edge(const float* __restrict__ xsrc,
                                                 const int* __restrict__ src_csr,
                                                 const int* __restrict__ dst_csr,
                                                 const int* __restrict__ eord,
                                                 const float* __restrict__ ewin,
                                                 float* __restrict__ ew_csr,
                                                 const float* __restrict__ unoise,
                                                 const float* __restrict__ epW1,
                                                 const float* __restrict__ epb1,
                                                 const float* __restrict__ epW2,
                                                 const float* __restrict__ epb2,
                                                 const float* __restrict__ alphap,
                                                 const float* __restrict__ Pb32,
                                                 const float* __restrict__ Pc32,
                                                 int* __restrict__ flagcnt,
                                                 int* __restrict__ flaglist,
                                                 float* __restrict__ out) {
    const int t = threadIdx.x;
    const int tx = t & 15, ty = t >> 4;

    __shared__ __align__(16) float ldsA[64 * 68];  // |dx| [dim][slot]
    __shared__ float ldsW[64 * 68];                // W1a [k][j]

    for (int idx = t; idx < D * D; idx += 256) {
        int k = idx >> 6, j = idx & 63;
        ldsW[k * 68 + j] = epW1[idx];
    }
    float b1f[4], w2f[4];
#pragma unroll
    for (int c = 0; c < 4; ++c) {
        b1f[c] = epb1[4 * tx + c];
        w2f[c] = epW2[4 * tx + c];
    }
    const float b2v = epb2[0];
    const float alpha = alphap[0];
    __syncthreads();

    const int eloc = t >> 2, q = t & 3;

    for (int tile = blockIdx.x; tile < NTILE; tile += gridDim.x) {
        const int base = tile * 64;

        // ---- stage |x_d - x_s| (f32, transposed). d-rows run-repeat (L1). --
        {
            const int pos = base + eloc;
            const int s = src_csr[pos], d = dst_csr[pos];
            const float* rs = xsrc + (size_t)s * D + q * 16;
            const float* rd = xsrc + (size_t)d * D + q * 16;
#pragma unroll
            for (int c = 0; c < 4; ++c) {
                const float4 fd = *(const float4*)(rd + 4 * c);
                const float4 fs = *(const float4*)(rs + 4 * c);
                const int dim = q * 16 + 4 * c;
                ldsA[(dim + 0) * 68 + eloc] = fabsf(fd.x - fs.x);
                ldsA[(dim + 1) * 68 + eloc] = fabsf(fd.y - fs.y);
                ldsA[(dim + 2) * 68 + eloc] = fabsf(fd.z - fs.z);
                ldsA[(dim + 3) * 68 + eloc] = fabsf(fd.w - fs.w);
            }
        }
        __syncthreads();

        // ---- 64x64x64 GEMM: f32 inputs, f32 accumulate, 4x4 per thread ----
        float acc[4][4];
#pragma unroll
        for (int r = 0; r < 4; ++r)
#pragma unroll
            for (int c = 0; c < 4; ++c) acc[r][c] = 0.0f;

#pragma unroll 4
        for (int k = 0; k < 64; ++k) {
            const float4 af = *(const float4*)&ldsA[k * 68 + 4 * ty];
            const float4 wf = *(const float4*)&ldsW[k * 68 + 4 * tx];
            const float av[4] = {af.x, af.y, af.z, af.w};
            const float wv[4] = {wf.x, wf.y, wf.z, wf.w};
#pragma unroll
            for (int r = 0; r < 4; ++r)
#pragma unroll
                for (int c = 0; c < 4; ++c) acc[r][c] += av[r] * wv[c];
        }
        __syncthreads();  // A dead -> reuse as f32 sred

        float* sred = ldsA;
        // ---- epilogue: + P' terms, +b1, relu, * w2, partial sums ----
#pragma unroll
        for (int r = 0; r < 4; ++r) {
            const int pos = base + 4 * ty + r;
            const int s = src_csr[pos], d = dst_csr[pos];
            const float4 pb = *(const float4*)(Pb32 + (size_t)d * D + 4 * tx);
            const float4 pc = *(const float4*)(Pc32 + (size_t)s * D + 4 * tx);
            float part = 0.0f;
            float h;
            h = acc[r][0] + pb.x + pc.x + b1f[0];
            if (h > 0.0f) part += h * w2f[0];
            h = acc[r][1] + pb.y + pc.y + b1f[1];
            if (h > 0.0f) part += h * w2f[1];
            h = acc[r][2] + pb.z + pc.z + b1f[2];
            if (h > 0.0f) part += h * w2f[2];
            h = acc[r][3] + pb.w + pc.w + b1f[3];
            if (h > 0.0f) part += h * w2f[3];
            sred[(4 * ty + r) * 17 + tx] = part;
        }
        __syncthreads();

        // ---- score reduce + RelaxedBernoulli sample (one lane per slot) ----
        if (t < 64) {
            float sc_ = b2v;
#pragma unroll
            for (int i = 0; i < 16; ++i) sc_ += sred[t * 17 + i];
            const int pos = base + t;
            const int e = eord[pos];
            const float u = unoise[(size_t)LAYER * NE + e];
            const float gn = logf(u) - log1pf(-u);
            const float mar = sc_ + gn;  // decision margin; samp == (mar > 0)
            bool deferred = false;
            if (fabsf(mar) < FIXTH) {
                int slot = atomicAdd(flagcnt, 1);
                if (slot < FLAGCAP) {
                    flaglist[slot] = pos;
                    deferred = true;  // k_fix decides + writes this edge
                }
            }
            if (!deferred) {
                const float pre = 1.0f / (1.0f + expf(-sc_));
                const bool samp = mar > 0.0f;
                const float ewo = (LAYER == 0) ? ewin[e] : ew_csr[pos];
                const float ewn = samp ? alpha * ewo + (1.0f - alpha) * pre : 0.0f;
                ew_csr[pos] = ewn;
                if (LAYER == NL - 1) {
                    out[OUT_EW + (size_t)e] = ewn;
                    out[OUT_PA + (size_t)e] = pre;
                }
            }
        }
        __syncthreads();
    }
}

// ---- exact f64 re-decision for near-threshold edges (one wave per edge) ----
template <int LAYER>
__global__ __launch_bounds__(256) void k_fix(const float* __restrict__ xsrc,
                                             const int* __restrict__ src_csr,
                                             const int* __restrict__ dst_csr,
                                             const int* __restrict__ eord,
                                             const float* __restrict__ ewin,
                                             float* __restrict__ ew_csr,
                                             const float* __restrict__ unoise,
                                             const float* __restrict__ epW1,
                                             const float* __restrict__ epb1,
                                             const float* __restrict__ epW2,
                                             const float* __restrict__ epb2,
                                             const float* __restrict__ alphap,
                                             const float* __restrict__ Pb32,
                                             const float* __restrict__ Pc32,
                                             const int* __restrict__ flagcnt,
                                             const int* __restrict__ flaglist,
                                             float* __restrict__ out) {
    const int n = min(flagcnt[0], FLAGCAP);
    __shared__ float dxs[4][D];
    const int w = threadIdx.x >> 6, lane = threadIdx.x & 63;
    const int nw = gridDim.x * 4;
    for (int i = blockIdx.x * 4 + w; i < n; i += nw) {
        const int pos = flaglist[i];
        const int s = src_csr[pos], d = dst_csr[pos];
        // |dx| from the same f32 inputs the main kernel staged
        dxs[w][lane] = fabsf(xsrc[(size_t)d * D + lane] - xsrc[(size_t)s * D + lane]);
        // wave-internal broadcast (same-wave DS in-order)
        double h = 0.0;
#pragma unroll
        for (int k = 0; k < D; ++k) h += (double)dxs[w][k] * (double)epW1[k * D + lane];
        h += (double)Pb32[(size_t)d * D + lane] + (double)Pc32[(size_t)s * D + lane] +
             (double)epb1[lane];
        double part = (h > 0.0) ? h * (double)epW2[lane] : 0.0;
#pragma unroll
        for (int off = 32; off; off >>= 1) part += __shfl_xor(part, off);
        if (lane == 0) {
            const double sc_ = part + (double)epb2[0];
            const int e = eord[pos];
            const double u = (double)unoise[(size_t)LAYER * NE + e];
            const double gn = log(u) - log1p(-u);
            const double pre = 1.0 / (1.0 + exp(-sc_));
            const bool samp = (sc_ + gn) > 0.0;
            const double ewo = (LAYER == 0) ? (double)ewin[e] : (double)ew_csr[pos];
            const double alpha = (double)alphap[0];
            const double ewn = samp ? alpha * ewo + (1.0 - alpha) * pre : 0.0;
            ew_csr[pos] = (float)ewn;
            if (LAYER == NL - 1) {
                out[OUT_EW + (size_t)e] = (float)ewn;
                out[OUT_PA + (size_t)e] = (float)pre;
            }
        }
    }
}

// ---- node update: CSR gather (row-parallel loads) + GIN mlp + BN partials --
// Lane = (slot e=0..3, quarter q=0..15). First 16 edges: 4 float4-load
// instructions x 4 rows each, issued back-to-back (named float4s, no arrays).
// f64 acc per (slot, 4 dims); tree-reduce slots (2x shfl_xor); + self; 16-lane
// rowbuf write; f64 matvec. Tail deg>16: masked chunks of 4. bnacc atomics
// block-reduced in LDS first.
template <int LAYER>
__global__ __launch_bounds__(256) void k_nodeup(const float* __restrict__ xsrc,
                                                const float* __restrict__ ew_csr,
                                                const int* __restrict__ src_csr,
                                                const int* __restrict__ rowptr,
                                                const float* __restrict__ ginW,
                                                const float* __restrict__ ginB,
                                                double* __restrict__ xh,
                                                double* __restrict__ bnacc) {
    __shared__ float wg[D * D];
    __shared__ double rowbuf[4][D];
    __shared__ double bn1[4][D];
    __shared__ double bn2[4][D];
    const int t = threadIdx.x, w = t >> 6, lane = t & 63;
    const int e = lane >> 4, q = lane & 15;  // slot, quarter (dims 4q..4q+3)
    for (int idx = t; idx < D * D; idx += 256) wg[idx] = ginW[LAYER * D * D + idx];
    const double bj = (double)ginB[LAYER * D + lane];
    __syncthreads();
    double s1 = 0.0, s2 = 0.0;
    const int nwaves = gridDim.x * 4;
    for (int n = blockIdx.x * 4 + w; n < NN; n += nwaves) {
        const int rs = rowptr[n], re = rowptr[n + 1];
        const int deg = re - rs;
        // ---- first 16 edges: 4 masked slots x 4 chunks, all loads up front
        const int i0 = rs + ((e < deg) ? e : 0);
        const int i1 = rs + ((4 + e < deg) ? 4 + e : 0);
        const int i2 = rs + ((8 + e < deg) ? 8 + e : 0);
        const int i3 = rs + ((12 + e < deg) ? 12 + e : 0);
        const float w0 = (e < deg) ? ew_csr[i0] : 0.f;
        const float w1 = (4 + e < deg) ? ew_csr[i1] : 0.f;
        const float w2 = (8 + e < deg) ? ew_csr[i2] : 0.f;
        const float w3 = (12 + e < deg) ? ew_csr[i3] : 0.f;
        const int s0 = src_csr[i0], s1_ = src_csr[i1];
        const int s2_ = src_csr[i2], s3_ = src_csr[i3];
        const float4 r0 = *(const float4*)(xsrc + (size_t)s0 * D + 4 * q);
        const float4 r1 = *(const float4*)(xsrc + (size_t)s1_ * D + 4 * q);
        const float4 r2 = *(const float4*)(xsrc + (size_t)s2_ * D + 4 * q);
        const float4 r3 = *(const float4*)(xsrc + (size_t)s3_ * D + 4 * q);
        const float4 rf = *(const float4*)(xsrc + (size_t)n * D + 4 * q);  // self
        double a0 = (double)w0 * (double)r0.x;
        double a1 = (double)w0 * (double)r0.y;
        double a2 = (double)w0 * (double)r0.z;
        double a3 = (double)w0 * (double)r0.w;
        a0 += (double)w1 * (double)r1.x;
        a1 += (double)w1 * (double)r1.y;
        a2 += (double)w1 * (double)r1.z;
        a3 += (double)w1 * (double)r1.w;
        a0 += (double)w2 * (double)r2.x;
        a1 += (double)w2 * (double)r2.y;
        a2 += (double)w2 * (double)r2.z;
        a3 += (double)w2 * (double)r2.w;
        a0 += (double)w3 * (double)r3.x;
        a1 += (double)w3 * (double)r3.y;
        a2 += (double)w3 * (double)r3.z;
        a3 += (double)w3 * (double)r3.w;
        // ---- tail: edges beyond 16, masked chunks of 4 (wave-uniform bound)
        for (int k = rs + 16; k < re; k += 4) {
            const int kk = k + e;
            const bool v = kk < re;
            const float wt = v ? ew_csr[kk] : 0.f;
            const int st = src_csr[v ? kk : rs];
            const float4 rt = *(const float4*)(xsrc + (size_t)st * D + 4 * q);
            a0 += (double)wt * (double)rt.x;
            a1 += (double)wt * (double)rt.y;
            a2 += (double)wt * (double)rt.z;
            a3 += (double)wt * (double)rt.w;
        }
        // ---- tree-reduce the 4 slots (lanes differing in bits 4,5) ----
        a0 += __shfl_xor(a0, 16);
        a1 += __shfl_xor(a1, 16);
        a2 += __shfl_xor(a2, 16);
        a3 += __shfl_xor(a3, 16);
        a0 += __shfl_xor(a0, 32);
        a1 += __shfl_xor(a1, 32);
        a2 += __shfl_xor(a2, 32);
        a3 += __shfl_xor(a3, 32);
        // ---- + self, publish to rowbuf (same-wave DS in-order) ----
        if (e == 0) {
            rowbuf[w][4 * q + 0] = a0 + (double)rf.x;
            rowbuf[w][4 * q + 1] = a1 + (double)rf.y;
            rowbuf[w][4 * q + 2] = a2 + (double)rf.z;
            rowbuf[w][4 * q + 3] = a3 + (double)rf.w;
        }
        // ---- GIN matvec (f64) ----
        double h = bj;
#pragma unroll
        for (int i = 0; i < D; ++i) h += rowbuf[w][i] * (double)wg[i * D + lane];
        h = h > 0.0 ? h : 0.0;
        xh[(size_t)n * D + lane] = h;
        s1 += h;
        s2 += h * h;
    }
    // ---- block-level reduce, then 2 atomics per lane-column per block ----
    bn1[w][lane] = s1;
    bn2[w][lane] = s2;
    __syncthreads();
    if (w == 0) {
        atomAdd64(&bnacc[lane], bn1[0][lane] + bn1[1][lane] + bn1[2][lane] + bn1[3][lane]);
        atomAdd64(&bnacc[64 + lane], bn2[0][lane] + bn2[1][lane] + bn2[2][lane] + bn2[3][lane]);
    }
}

// ---- BN finalize ----
__global__ __launch_bounds__(64) void k_bnfin(int layer, const float* __restrict__ gamma,
                                              const float* __restrict__ beta,
                                              const double* __restrict__ bnacc,
                                              double* __restrict__ bnsc) {
    int j = threadIdx.x;
    double mu = bnacc[j] * (1.0 / NN);
    double var = bnacc[64 + j] * (1.0 / NN) - mu * mu;
    double sc = (double)gamma[layer * D + j] / sqrt(var + 1e-5);
    bnsc[j] = sc;
    bnsc[64 + j] = (double)beta[layer * D + j] - mu * sc;
}

// ---- BN apply -> x64 (+x32 mirror for edge/nodeup staging; final out) ----
template <int LAYER>
__global__ __launch_bounds__(256) void k_bnapply(const double* __restrict__ bnsc,
                                                 const double* __restrict__ xh,
                                                 double* __restrict__ x64,
                                                 float* __restrict__ x32,
                                                 float* __restrict__ out) {
    size_t stride = (size_t)gridDim.x * 256;
    for (size_t i = (size_t)blockIdx.x * 256 + threadIdx.x; i < (size_t)NN * D; i += stride) {
        int j = (int)(i & 63);
        double v = bnsc[j] * xh[i] + bnsc[64 + j];
        x64[i] = v;
        if (LAYER == 0) x32[i] = (float)v;
        if (LAYER == NL - 1) out[OUT_X + i] = (float)v;
    }
}

// ---- attention pooling, parallelized: 4 kernels ----
__global__ __launch_bounds__(256) void k_att1(const double* __restrict__ x64,
                                              const double* __restrict__ c64,
                                              double* __restrict__ sc,
                                              double* __restrict__ bmax) {
    const int blk = blockIdx.x, t = threadIdx.x, w = t >> 6, lane = t & 63;
    const int g = blk >> 6;
    __shared__ double wmax[4];
    const double cj = c64[g * D + lane];
    double locmax = -1e300;
    for (int m = 0; m < 16; ++m) {
        const int n = blk * 64 + w * 16 + m;
        double v = x64[(size_t)n * D + lane] * cj;
#pragma unroll
        for (int off = 32; off; off >>= 1) v += __shfl_xor(v, off);
        if (lane == 0) sc[n] = v;
        locmax = fmax(locmax, v);
    }
    if (lane == 0) wmax[w] = locmax;
    __syncthreads();
    if (t == 0) bmax[blk] = fmax(fmax(wmax[0], wmax[1]), fmax(wmax[2], wmax[3]));
}

__global__ __launch_bounds__(64) void k_att2(const double* __restrict__ bmax,
                                             double* __restrict__ mxg,
                                             double* __restrict__ num,
                                             double* __restrict__ den) {
    const int g = blockIdx.x, t = threadIdx.x;
    double m = bmax[g * 64 + t];
#pragma unroll
    for (int off = 32; off; off >>= 1) m = fmax(m, __shfl_xor(m, off));
    if (t == 0) {
        mxg[g] = m;
        den[g] = 0.0;
    }
    num[g * D + t] = 0.0;
}

__global__ __launch_bounds__(256) void k_att3(const double* __restrict__ x64,
                                              const double* __restrict__ sc,
                                              const double* __restrict__ mxg,
                                              double* __restrict__ num,
                                              double* __restrict__ den) {
    const int blk = blockIdx.x, t = threadIdx.x, w = t >> 6, lane = t & 63;
    const int g = blk >> 6;
    __shared__ double cp[4][D];
    __shared__ double wes[4];
    const double mx = mxg[g];
    double accj = 0.0, esum = 0.0;
    for (int m = 0; m < 16; ++m) {
        const int n = blk * 64 + w * 16 + m;
        const double e = exp(sc[n] - mx);
        accj += e * x64[(size_t)n * D + lane];
        esum += e;
    }
    cp[w][lane] = accj;
    if (lane == 0) wes[w] = esum;
    __syncthreads();
    if (t < D) {
        atomAdd64(&num[g * D + t], cp[0][t] + cp[1][t] + cp[2][t] + cp[3][t]);
        if (t == 0) atomAdd64(&den[g], wes[0] + wes[1] + wes[2] + wes[3]);
    }
}

__global__ __launch_bounds__(64) void k_att4(const double* __restrict__ num,
                                             const double* __restrict__ den,
                                             double* __restrict__ c64) {
    const int g = blockIdx.x, t = threadIdx.x;
    c64[g * D + t] = num[g * D + t] / den[g];
}

// ---- head: relu(x@W1+b1)@W2+b2 for all nodes + 16 centroid rows (f32) ----
__global__ __launch_bounds__(256) void k_head(const double* __restrict__ x64,
                                              const double* __restrict__ c64,
                                              const float* __restrict__ hW1,
                                              const float* __restrict__ hb1,
                                              const float* __restrict__ hW2,
                                              const float* __restrict__ hb2,
                                              float* __restrict__ out) {
    __shared__ float w1[D * D];
    __shared__ float w2[D * D];
    __shared__ float xr[4][D];
    __shared__ float hr[4][D];
    int tid = threadIdx.x, w = tid >> 6, j = tid & 63;
    for (int idx = tid; idx < D * D; idx += 256) {
        w1[idx] = hW1[idx];
        w2[idx] = hW2[idx];
    }
    const float b1j = hb1[j];
    const float b2j = hb2[j];
    __syncthreads();
    const int ROWS = NN + BSZ;
    for (int grp = blockIdx.x; grp * 4 < ROWS; grp += gridDim.x) {
        int r = grp * 4 + w;
        bool valid = r < ROWS;
        float xv = 0.f;
        if (valid)
            xv = (r < NN) ? (float)x64[(size_t)r * D + j] : (float)c64[(size_t)(r - NN) * D + j];
        xr[w][j] = xv;
        __syncthreads();
        if (valid) {
            float h = b1j;
#pragma unroll
            for (int i = 0; i < D; ++i) h += xr[w][i] * w1[i * D + j];
            hr[w][j] = h > 0.f ? h : 0.f;
        }
        __syncthreads();
        if (valid) {
            float o = b2j;
#pragma unroll
            for (int i = 0; i < D; ++i) o += hr[w][i] * w2[i * D + j];
            if (r < NN) {
                out[OUT_XL + (size_t)r * D + j] = o;
            } else {
                size_t cr = (size_t)(r - NN) * D + j;
                out[OUT_CL + cr] = o;
                out[OUT_C + cr] = (float)c64[cr];
            }
        }
        __syncthreads();
    }
}

extern "C" void kernel_launch(void* const* d_in, const int* in_sizes, int n_in,
                              void* d_out, int out_size, void* d_ws, size_t ws_size,
                              hipStream_t stream) {
    const float* xin    = (const float*)d_in[0];
    const int*   ei     = (const int*)d_in[1];
    const float* ewin   = (const float*)d_in[2];
    const float* unoise = (const float*)d_in[5];
    const float* epW1   = (const float*)d_in[6];
    const float* epb1   = (const float*)d_in[7];
    const float* epW2   = (const float*)d_in[8];
    const float* epb2   = (const float*)d_in[9];
    const float* alphap = (const float*)d_in[10];
    const float* ginW   = (const float*)d_in[11];
    const float* ginB   = (const float*)d_in[12];
    const float* bng    = (const float*)d_in[13];
    const float* bnb    = (const float*)d_in[14];
    const float* hW1    = (const float*)d_in[15];
    const float* hb1    = (const float*)d_in[16];
    const float* hW2    = (const float*)d_in[17];
    const float* hb2    = (const float*)d_in[18];
    float* out = (float*)d_out;
    const int* esrc = ei;
    const int* edst = ei + NE;

    char* ws = (char*)d_ws;
    const size_t SZ = (size_t)NN * D * sizeof(double);  // 33554432
    double* x64  = (double*)(ws);
    // Pb/Pc (k_P->k_edge) and xh (k_nodeup->k_bnapply): disjoint live ranges.
    float*  Pb32 = (float*)(ws + SZ);
    float*  Pc32 = (float*)(ws + SZ + SZ / 2);
    double* xh   = (double*)(ws + SZ);
    float*  x32  = (float*)(ws + 2 * SZ);                       // NN*D*4 = 16MB
    float*  ew_csr = (float*)(ws + 2 * SZ + SZ / 2);            // NE*4 (slot is NE*8)
    double* sc   = (double*)(ws + 2 * SZ + SZ / 2 + (size_t)NE * 8);  // NN*8
    char*   p    = ws + 2 * SZ + SZ / 2 + (size_t)NE * 8 + (size_t)NN * 8;
    double* c64  = (double*)p;          p += BSZ * D * 8;
    double* qb   = (double*)p;          p += BSZ * D * 8;
    double* qc   = (double*)p;          p += BSZ * D * 8;
    double* bnacc = (double*)p;         p += 128 * 8;
    double* bnsc  = (double*)p;         p += 128 * 8;
    double* bmax  = (double*)p;         p += 1024 * 8;
    double* mxg   = (double*)p;         p += 16 * 8;
    double* num   = (double*)p;         p += BSZ * D * 8;
    double* den   = (double*)p;         p += 16 * 8;
    // CSR
    int* cnt     = (int*)p;             p += (size_t)NN * 4;
    int* rowptr  = (int*)p;             p += (size_t)(NN + 1) * 4 + 4;
    int* cursor  = (int*)p;             p += (size_t)NN * 4;
    int* bsum    = (int*)p;             p += 256 * 4;
    int* eord    = (int*)p;             p += (size_t)NE * 4;
    int* src_csr = (int*)p;             p += (size_t)NE * 4;
    int* dst_csr = (int*)p;             p += (size_t)NE * 4;
    // near-threshold fixup list
    int* flagcnt  = (int*)p;            p += 8;
    int* flaglist = (int*)p;            p += (size_t)FLAGCAP * 4;

    // ---- CSR build (dst static) ----
    hipMemsetAsync(cnt, 0, (size_t)NN * 4, stream);
    k_deg<<<1024, 256, 0, stream>>>(edst, cnt);
    k_scan1<<<256, 256, 0, stream>>>(cnt, rowptr, bsum);
    k_scan2<<<1, 256, 0, stream>>>(bsum);
    k_scan3<<<256, 256, 0, stream>>>(bsum, rowptr, cursor);
    k_fill<<<1024, 256, 0, stream>>>(esrc, edst, cursor, eord, src_csr, dst_csr);

    hipMemsetAsync(c64, 0, (size_t)BSZ * D * 8, stream);
    k_centroid0<<<BSZ * 8, 256, 0, stream>>>(xin, c64);

    // ---------------- layer 0 ----------------
    k_qbc<<<4, 256, 0, stream>>>(c64, epW1, qb, qc);
    k_P<0><<<1024, 256, 0, stream>>>(xin, x64, epW1, qb, qc, Pb32, Pc32, bnacc);
    hipMemsetAsync(flagcnt, 0, 4, stream);
    k_edge<0><<<2048, 256, 0, stream>>>(xin, src_csr, dst_csr, eord, ewin, ew_csr, unoise,
                                        epW1, epb1, epW2, epb2, alphap, Pb32, Pc32,
                                        flagcnt, flaglist, out);
    k_fix<0><<<64, 256, 0, stream>>>(xin, src_csr, dst_csr, eord, ewin, ew_csr, unoise,
                                     epW1, epb1, epW2, epb2, alphap, Pb32, Pc32,
                                     flagcnt, flaglist, out);
    k_nodeup<0><<<2048, 256, 0, stream>>>(xin, ew_csr, src_csr, rowptr, ginW, ginB,
                                          xh, bnacc);
    k_bnfin<<<1, 64, 0, stream>>>(0, bng, bnb, bnacc, bnsc);
    k_bnapply<0><<<2048, 256, 0, stream>>>(bnsc, xh, x64, x32, out);
    k_att1<<<1024, 256, 0, stream>>>(x64, c64, sc, bmax);
    k_att2<<<16, 64, 0, stream>>>(bmax, mxg, num, den);
    k_att3<<<1024, 256, 0, stream>>>(x64, sc, mxg, num, den);
    k_att4<<<16, 64, 0, stream>>>(num, den, c64);

    // ---------------- layer 1 ----------------
    k_qbc<<<4, 256, 0, stream>>>(c64, epW1, qb, qc);
    k_P<1><<<1024, 256, 0, stream>>>(xin, x64, epW1, qb, qc, Pb32, Pc32, bnacc);
    hipMemsetAsync(flagcnt, 0, 4, stream);
    k_edge<1><<<2048, 256, 0, stream>>>(x32, src_csr, dst_csr, eord, ewin, ew_csr, unoise,
                                        epW1, epb1, epW2, epb2, alphap, Pb32, Pc32,
                                        flagcnt, flaglist, out);
    k_fix<1><<<64, 256, 0, stream>>>(x32, src_csr, dst_csr, eord, ewin, ew_csr, unoise,
                                     epW1, epb1, epW2, epb2, alphap, Pb32, Pc32,
                                     flagcnt, flaglist, out);
    k_nodeup<1><<<2048, 256, 0, stream>>>(x32, ew_csr, src_csr, rowptr, ginW, ginB,
                                          xh, bnacc);
    k_bnfin<<<1, 64, 0, stream>>>(1, bng, bnb, bnacc, bnsc);
    k_bnapply<1><<<2048, 256, 0, stream>>>(bnsc, xh, x64, x32, out);
    k_att1<<<1024, 256, 0, stream>>>(x64, c64, sc, bmax);
    k_att2<<<16, 64, 0, stream>>>(bmax, mxg, num, den);
    k_att3<<<1024, 256, 0, stream>>>(x64, sc, mxg, num, den);
    k_att4<<<16, 64, 0, stream>>>(num, den, c64);

    // ---------------- heads + centroid output ----------------
    k_head<<<2048, 256, 0, stream>>>(x64, c64, hW1, hb1, hW2, hb2, out);
}